// Round 3
// baseline (4306.049 us; speedup 1.0000x reference)
//
#include <hip/hip_runtime.h>
#include <hip/hip_bf16.h>

#define E_TOT 20000
#define KNB   20
#define KIN   356
#define KPAD  384
#define F1d   512
#define F2d   128
#define EPSv  1e-5f

typedef __bf16  bf16x8 __attribute__((ext_vector_type(8)));
typedef __bf16  bf16x4 __attribute__((ext_vector_type(4)));
typedef float   f32x4  __attribute__((ext_vector_type(4)));

// ---------------- prep: weight reorder into MFMA B-fragment layout ----------
// frag = kstep*(N/16) + coltile ; element (lane,j): k = ks*32 + (lane>>4)*8 + j,
// n = ct*16 + (lane&15). Rows k>=K are zero-padded.
__global__ void reorder_w(const float* __restrict__ src, __bf16* __restrict__ dst,
                          int K, int N, int Kpad) {
    int idx = blockIdx.x * 256 + threadIdx.x;
    int total = Kpad * N;
    if (idx >= total) return;
    int frag   = idx >> 9;
    int within = idx & 511;
    int lane   = within >> 3;
    int j      = within & 7;
    int nct = N >> 4;
    int ks  = frag / nct;
    int ct  = frag - ks * nct;
    int k = ks * 32 + ((lane >> 4) << 3) + j;
    int n = (ct << 4) + (lane & 15);
    float v = (k < K) ? src[(size_t)k * N + n] : 0.f;
    dst[idx] = (__bf16)v;
}

// BN(eval) folded with fc1s bias: y = h*escale + eshift
__global__ void bn_prep(const float* __restrict__ fc1s_b, const float* __restrict__ g,
                        const float* __restrict__ b, const float* __restrict__ m,
                        const float* __restrict__ v, float* __restrict__ escale,
                        float* __restrict__ eshift) {
    int c = blockIdx.x * 256 + threadIdx.x;
    if (c >= F1d) return;
    float sc = g[c] * rsqrtf(v[c] + EPSv);
    escale[c] = sc;
    eshift[c] = (fc1s_b[c] - m[c]) * sc + b[c];
}

// ---------------- source branch: 32 rows/block, 4 waves --------------------
__launch_bounds__(256, 3)
__global__ void src_kernel(const float* __restrict__ memory,
                           const __bf16* __restrict__ W1sf,
                           const float* __restrict__ escale,
                           const float* __restrict__ eshift,
                           const __bf16* __restrict__ W2sf,
                           const float* __restrict__ fc2s_b,
                           const int* __restrict__ source_nodes,
                           float* __restrict__ out) {
    __shared__ __align__(16) __bf16 Xs[32][136];   // 128 + 8 pad
    __shared__ __align__(16) __bf16 hs[32][520];   // 512 + 8 pad
    __shared__ int snode[32];

    const int t = threadIdx.x;
    const int lane = t & 63;
    const int w = t >> 6;            // 4 waves
    const int l15 = lane & 15, l4 = lane >> 4;
    const int e0 = blockIdx.x * 32;

    if (t < 32) snode[t] = source_nodes[e0 + t];
    __syncthreads();

    // gather 32 rows x 128 f32 -> bf16
    #pragma unroll
    for (int it = 0; it < 4; ++it) {
        int cid = t + it * 256;
        int row = cid >> 5;
        int part = cid & 31;
        float4 v = *(const float4*)(memory + (size_t)snode[row] * 128 + part * 4);
        bf16x4 o;
        o[0] = (__bf16)v.x; o[1] = (__bf16)v.y; o[2] = (__bf16)v.z; o[3] = (__bf16)v.w;
        *(bf16x4*)&Xs[row][part * 4] = o;
    }
    __syncthreads();

    // GEMM1s: [32x128]x[128x512]; wave owns coltiles 8w..8w+7
    f32x4 acc[2][8];
    #pragma unroll
    for (int rt = 0; rt < 2; ++rt)
        #pragma unroll
        for (int ci = 0; ci < 8; ++ci) acc[rt][ci] = (f32x4){0.f, 0.f, 0.f, 0.f};

    for (int ks = 0; ks < 4; ++ks) {
        bf16x8 a[2];
        #pragma unroll
        for (int rt = 0; rt < 2; ++rt)
            a[rt] = *(const bf16x8*)&Xs[rt * 16 + l15][ks * 32 + l4 * 8];
        #pragma unroll
        for (int ci = 0; ci < 8; ++ci) {
            bf16x8 b = *(const bf16x8*)&W1sf[(size_t)((ks * 32 + (w * 8 + ci)) * 512) + lane * 8];
            #pragma unroll
            for (int rt = 0; rt < 2; ++rt)
                acc[rt][ci] = __builtin_amdgcn_mfma_f32_16x16x32_bf16(a[rt], b, acc[rt][ci], 0, 0, 0);
        }
    }

    // BN + ReLU -> hs (bf16)
    float es[8], eh[8];
    #pragma unroll
    for (int ci = 0; ci < 8; ++ci) {
        int col = (w * 8 + ci) * 16 + l15;
        es[ci] = escale[col]; eh[ci] = eshift[col];
    }
    #pragma unroll
    for (int rt = 0; rt < 2; ++rt)
        #pragma unroll
        for (int ci = 0; ci < 8; ++ci)
            #pragma unroll
            for (int r = 0; r < 4; ++r) {
                int row = rt * 16 + l4 * 4 + r;
                int col = (w * 8 + ci) * 16 + l15;
                float y = fmaxf(acc[rt][ci][r] * es[ci] + eh[ci], 0.f);
                hs[row][col] = (__bf16)y;
            }
    __syncthreads();

    // GEMM2s: [32x512]x[512x128]; wave owns coltiles {2w,2w+1}
    f32x4 acc2[2][2];
    #pragma unroll
    for (int rt = 0; rt < 2; ++rt)
        #pragma unroll
        for (int ci = 0; ci < 2; ++ci) acc2[rt][ci] = (f32x4){0.f, 0.f, 0.f, 0.f};

    for (int ks = 0; ks < 16; ++ks) {
        bf16x8 a[2];
        #pragma unroll
        for (int rt = 0; rt < 2; ++rt)
            a[rt] = *(const bf16x8*)&hs[rt * 16 + l15][ks * 32 + l4 * 8];
        #pragma unroll
        for (int ci = 0; ci < 2; ++ci) {
            bf16x8 b = *(const bf16x8*)&W2sf[(size_t)((ks * 8 + (w * 2 + ci)) * 512) + lane * 8];
            #pragma unroll
            for (int rt = 0; rt < 2; ++rt)
                acc2[rt][ci] = __builtin_amdgcn_mfma_f32_16x16x32_bf16(a[rt], b, acc2[rt][ci], 0, 0, 0);
        }
    }

    #pragma unroll
    for (int rt = 0; rt < 2; ++rt)
        #pragma unroll
        for (int ci = 0; ci < 2; ++ci)
            #pragma unroll
            for (int r = 0; r < 4; ++r) {
                int row = rt * 16 + l4 * 4 + r;
                int col = (w * 2 + ci) * 16 + l15;
                out[(size_t)(e0 + row) * 384 + col] = acc2[rt][ci][r] + fc2s_b[col];
            }
}

// ---------------- TPPR branches: 4 edges (80 rows)/block, 8 waves ----------
__launch_bounds__(512, 4)
__global__ void tppr_kernel(const float* __restrict__ memory,
                            const float* __restrict__ edge_tbl,
                            const float* __restrict__ sel_dt,
                            const float* __restrict__ sel_w,
                            const float* __restrict__ time_w,
                            const float* __restrict__ time_b,
                            const __bf16* __restrict__ W1f,
                            const float* __restrict__ fc1_b,
                            const float* __restrict__ ln_g,
                            const float* __restrict__ ln_b,
                            const __bf16* __restrict__ W2f,
                            const float* __restrict__ fc2_b,
                            const int* __restrict__ sel_nodes,
                            const int* __restrict__ sel_edges,
                            float* __restrict__ out) {
    __shared__ __align__(16) __bf16 X[80][392];    // 384 + 8 pad (bank-stride 4)
    __shared__ __align__(16) float wsacc[4][512];  // weighted sum of relu(ln(h))
    __shared__ float ssum[80], ssq[80];
    __shared__ int   ridx[80], reidx[80];
    __shared__ float rdt[80], rw[80], wnrm[80];
    __shared__ float swsum[4];

    const int t = threadIdx.x;
    const int lane = t & 63;
    const int w = t >> 6;            // 8 waves
    const int l15 = lane & 15, l4 = lane >> 4;
    const int bid = blockIdx.x;
    const int branch = bid / 5000;
    const int e0 = (bid - branch * 5000) * 4;
    const int base = branch * E_TOT * KNB + e0 * KNB;

    // zero accumul. buffers; stage indices
    for (int i = t; i < 4 * 512; i += 512) ((float*)wsacc)[i] = 0.f;
    if (t < 80) {
        ssum[t] = 0.f; ssq[t] = 0.f;
        ridx[t]  = sel_nodes[base + t];
        reidx[t] = sel_edges[base + t];
        rdt[t]   = sel_dt[base + t];
        rw[t]    = sel_w[base + t];
    }
    __syncthreads();

    if (t < 4) {
        float s = 0.f;
        #pragma unroll
        for (int k = 0; k < KNB; ++k) s += rw[t * KNB + k];
        swsum[t] = s;
    }

    // gather 80 rows x (128 node + 128 edge) f32 -> bf16
    #pragma unroll
    for (int it = 0; it < 10; ++it) {
        int cid = t + it * 512;
        int row = cid >> 6;
        int part = cid & 63;
        const float* src = (part < 32) ? (memory  + (size_t)ridx[row]  * 128)
                                       : (edge_tbl + (size_t)reidx[row] * 128);
        float4 v = *(const float4*)(src + (part & 31) * 4);
        bf16x4 o;
        o[0] = (__bf16)v.x; o[1] = (__bf16)v.y; o[2] = (__bf16)v.z; o[3] = (__bf16)v.w;
        *(bf16x4*)&X[row][part * 4] = o;
    }
    // time encoding: cols 256..355
    for (int id = t; id < 80 * 100; id += 512) {
        int row = id / 100;
        int j = id - row * 100;
        float arg = rdt[row] * time_w[j] + time_b[j];
        X[row][256 + j] = (__bf16)__cosf(arg);
    }
    // zero pad cols 356..383
    for (int id = t; id < 80 * 28; id += 512) {
        int row = id / 28;
        int j = id - row * 28;
        X[row][KIN + j] = (__bf16)0.f;
    }
    __syncthreads();

    if (t < 80) {
        float s = swsum[t / KNB];
        wnrm[t] = (s > 0.f) ? rw[t] / s : 0.f;
    }

    // GEMM1: [80x384]x[384x512]; wave owns coltiles 4w..4w+3
    f32x4 acc[5][4];
    #pragma unroll
    for (int rt = 0; rt < 5; ++rt)
        #pragma unroll
        for (int ci = 0; ci < 4; ++ci) acc[rt][ci] = (f32x4){0.f, 0.f, 0.f, 0.f};

    for (int ks = 0; ks < 12; ++ks) {
        bf16x8 a[5];
        #pragma unroll
        for (int rt = 0; rt < 5; ++rt)
            a[rt] = *(const bf16x8*)&X[rt * 16 + l15][ks * 32 + l4 * 8];
        #pragma unroll
        for (int ci = 0; ci < 4; ++ci) {
            bf16x8 b = *(const bf16x8*)&W1f[(size_t)((ks * 32 + (w * 4 + ci)) * 512) + lane * 8];
            #pragma unroll
            for (int rt = 0; rt < 5; ++rt)
                acc[rt][ci] = __builtin_amdgcn_mfma_f32_16x16x32_bf16(a[rt], b, acc[rt][ci], 0, 0, 0);
        }
    }

    // LN row stats (mean/var over 512 cols), bias included
    float fb[4];
    #pragma unroll
    for (int ci = 0; ci < 4; ++ci) fb[ci] = fc1_b[(w * 4 + ci) * 16 + l15];

    #pragma unroll
    for (int rt = 0; rt < 5; ++rt)
        #pragma unroll
        for (int r = 0; r < 4; ++r) {
            int row = rt * 16 + l4 * 4 + r;
            float s = 0.f, q = 0.f;
            #pragma unroll
            for (int ci = 0; ci < 4; ++ci) {
                float v = acc[rt][ci][r] + fb[ci];
                s += v; q += v * v;
            }
            atomicAdd(&ssum[row], s);
            atomicAdd(&ssq[row], q);
        }
    __syncthreads();

    if (t < 80) {
        float mu = ssum[t] * (1.f / 512.f);
        float var = ssq[t] * (1.f / 512.f) - mu * mu;
        ssum[t] = mu;
        ssq[t] = rsqrtf(var + EPSv);
    }
    __syncthreads();

    // LN + ReLU + weighted reduce over K -> wsacc[4][512]
    float gg[4], bb[4];
    #pragma unroll
    for (int ci = 0; ci < 4; ++ci) {
        int col = (w * 4 + ci) * 16 + l15;
        gg[ci] = ln_g[col]; bb[ci] = ln_b[col];
    }
    #pragma unroll
    for (int rt = 0; rt < 5; ++rt)
        #pragma unroll
        for (int r = 0; r < 4; ++r) {
            int row = rt * 16 + l4 * 4 + r;
            float mu = ssum[row], rs = ssq[row], wr = wnrm[row];
            int e = row / KNB;
            #pragma unroll
            for (int ci = 0; ci < 4; ++ci) {
                float v = acc[rt][ci][r] + fb[ci];
                float y = fmaxf((v - mu) * rs * gg[ci] + bb[ci], 0.f);
                atomicAdd(&wsacc[e][(w * 4 + ci) * 16 + l15], wr * y);
            }
        }
    __syncthreads();

    // GEMM2: [4(pad16)x512]x[512x128]; wave w owns coltile w
    f32x4 acc2 = (f32x4){0.f, 0.f, 0.f, 0.f};
    for (int ks = 0; ks < 16; ++ks) {
        bf16x8 a2;
        if (l15 < 4) {
            const float* p = &wsacc[l15][ks * 32 + l4 * 8];
            #pragma unroll
            for (int j = 0; j < 8; ++j) a2[j] = (__bf16)p[j];
        } else {
            #pragma unroll
            for (int j = 0; j < 8; ++j) a2[j] = (__bf16)0.f;
        }
        bf16x8 b2 = *(const bf16x8*)&W2f[(size_t)((ks * 8 + w) * 512) + lane * 8];
        acc2 = __builtin_amdgcn_mfma_f32_16x16x32_bf16(a2, b2, acc2, 0, 0, 0);
    }

    if (lane < 16) {   // l4==0 -> rows 0..3 = local edges
        int col = w * 16 + l15;
        float b2c = fc2_b[col];
        #pragma unroll
        for (int r = 0; r < 4; ++r) {
            float flag = (swsum[r] > 0.f) ? 1.f : 0.f;
            out[(size_t)(e0 + r) * 384 + (branch + 1) * 128 + col] = acc2[r] + b2c * flag;
        }
    }
}

// ---------------------------------------------------------------------------
extern "C" void kernel_launch(void* const* d_in, const int* in_sizes, int n_in,
                              void* d_out, int out_size, void* d_ws, size_t ws_size,
                              hipStream_t stream) {
    const float* memory      = (const float*)d_in[0];
    const float* edge_tbl    = (const float*)d_in[1];
    const float* sel_dt      = (const float*)d_in[2];
    const float* sel_w       = (const float*)d_in[3];
    const float* time_w      = (const float*)d_in[4];
    const float* time_b      = (const float*)d_in[5];
    const float* fc1_w       = (const float*)d_in[6];
    const float* fc1_b       = (const float*)d_in[7];
    const float* ln1_g       = (const float*)d_in[8];
    const float* ln1_b       = (const float*)d_in[9];
    const float* fc2_w       = (const float*)d_in[10];
    const float* fc2_b       = (const float*)d_in[11];
    const float* fc1s_w      = (const float*)d_in[12];
    const float* fc1s_b      = (const float*)d_in[13];
    const float* bn_g        = (const float*)d_in[14];
    const float* bn_b        = (const float*)d_in[15];
    const float* bn_m        = (const float*)d_in[16];
    const float* bn_v        = (const float*)d_in[17];
    const float* fc2s_w      = (const float*)d_in[18];
    const float* fc2s_b      = (const float*)d_in[19];
    const int* source_nodes  = (const int*)d_in[20];
    const int* sel_nodes     = (const int*)d_in[21];
    const int* sel_edges     = (const int*)d_in[22];
    float* out = (float*)d_out;

    char* ws = (char*)d_ws;
    __bf16* W1f    = (__bf16*)(ws + 0);        // 384*512  = 196608 el -> 393216 B
    __bf16* W2f    = (__bf16*)(ws + 393216);   // 512*128  =  65536 el -> 131072 B
    __bf16* W1sf   = (__bf16*)(ws + 524288);   // 128*512  =  65536 el
    __bf16* W2sf   = (__bf16*)(ws + 655360);   // 512*128  =  65536 el
    float*  escale = (float*)(ws + 786432);    // 512 f32
    float*  eshift = (float*)(ws + 788480);    // 512 f32

    reorder_w<<<768, 256, 0, stream>>>(fc1_w,  W1f,  KIN, F1d, KPAD);
    reorder_w<<<256, 256, 0, stream>>>(fc2_w,  W2f,  F1d, F2d, F1d);
    reorder_w<<<256, 256, 0, stream>>>(fc1s_w, W1sf, 128, F1d, 128);
    reorder_w<<<256, 256, 0, stream>>>(fc2s_w, W2sf, F1d, F2d, F1d);
    bn_prep<<<2, 256, 0, stream>>>(fc1s_b, bn_g, bn_b, bn_m, bn_v, escale, eshift);

    src_kernel<<<625, 256, 0, stream>>>(memory, W1sf, escale, eshift, W2sf, fc2s_b,
                                        source_nodes, out);
    tppr_kernel<<<10000, 512, 0, stream>>>(memory, edge_tbl, sel_dt, sel_w,
                                           time_w, time_b, W1f, fc1_b, ln1_g, ln1_b,
                                           W2f, fc2_b, sel_nodes, sel_edges, out);
}